// Round 12
// baseline (215.162 us; speedup 1.0000x reference)
//
#include <hip/hip_runtime.h>
#include <cstdint>

// Problem constants (from reference)
constexpr int B_   = 4096;
constexpr int T_   = 512;
constexpr int DIN  = 10;
constexpr int H_   = 20;
constexpr int DOUT = 2;

typedef float v2f __attribute__((ext_vector_type(2)));
typedef float v4f __attribute__((ext_vector_type(4)));

// One v_pk_fma_f32: two fp32 FMAs per instruction (gfx950 packed-FP32).
__device__ __forceinline__ v2f pkfma(v2f a, v2f b, v2f c) {
    return __builtin_elementwise_fma(a, b, c);
}

__device__ __forceinline__ float fast_tanh(float v) {
    // tanh(v) = 1 - 2/(exp2(2*log2e*v)+1): exact saturation at +/-inf
    float e = __builtin_amdgcn_exp2f(v * 2.885390082f);
    float r = __builtin_amdgcn_rcpf(e + 1.0f);
    return fmaf(-2.0f, r, 1.0f);
}

// Wave-internal producer/consumer RNN: ONE sample per wave.
//   lanes  0..19 (set0): h1(tau)   = tanh(xp(tau) + wh0 . h1(tau-1))
//   lanes 20..39 (set1): h2(tau-1) = tanh(bias1 + wi1 . h1(tau-1) + wh1 . h2(tau-2))
//   lanes 40..63: spare (write to unused LDS rows, results discarded)
// Branchless: per-lane U/V weight rows select the role; V=0 for set0; one
// cndmask selects the bias/xp base. ONE LDS write + one batched broadcast
// read per step (wave-uniform addresses -> zero bank conflicts).
// 4096 waves = 4 waves/SIMD: each wave's exchange latency hides under the
// other three waves' issue (TLP instead of unhideable per-wave latency).
extern "C" __global__ void __launch_bounds__(64, 4)
rnn_ws(const float* __restrict__ x,
       const float* __restrict__ w_ih0, const float* __restrict__ w_hh0,
       const float* __restrict__ b_ih0, const float* __restrict__ b_hh0,
       const float* __restrict__ w_ih1, const float* __restrict__ w_hh1,
       const float* __restrict__ b_ih1, const float* __restrict__ b_hh1,
       const float* __restrict__ fc_w, const float* __restrict__ fc_b,
       float* __restrict__ out)
{
    const int  lane = threadIdx.x;
    const int  i    = lane % H_;                 // weight row 0..19
    const bool s0   = (lane < H_);               // layer-0 lanes
    const bool s1   = (lane >= H_) && (lane < 2 * H_);  // layer-1 lanes
    const int  samp = blockIdx.x;                // grid == B_ exactly

    __shared__ __align__(16) float hs[64];       // [0..19]=h1, [20..39]=h2, rest spare

    // ---- per-lane weight rows (roles selected at init, branchless in loop) ----
    // U: set0 -> w_hh0 row i ; set1 -> w_ih1 row i ; spare lanes -> w_hh0 (harmless)
    v2f U[10];
    {
        const v4f* p = reinterpret_cast<const v4f*>((s1 ? w_ih1 : w_hh0) + i * H_);
        #pragma unroll
        for (int k = 0; k < 5; ++k) {
            v4f v = p[k];
            U[2*k]   = (v2f){v.x, v.y};
            U[2*k+1] = (v2f){v.z, v.w};
        }
    }
    // V: set1 -> w_hh1 row i ; others -> 0 (their V-dot contributes nothing)
    v2f V[10];
    {
        const v4f* p = reinterpret_cast<const v4f*>(w_hh1 + i * H_);
        const float m = s1 ? 1.0f : 0.0f;
        #pragma unroll
        for (int k = 0; k < 5; ++k) {
            v4f v = p[k];
            V[2*k]   = (v2f){v.x * m, v.y * m};
            V[2*k+1] = (v2f){v.z * m, v.w * m};
        }
    }
    // Wx: set0 -> w_ih0 row i ; others -> 0 (their xp collapses to bias0, unused)
    v2f Wx[5];
    {
        const v2f* p = reinterpret_cast<const v2f*>(w_ih0 + i * DIN);
        const float m = s0 ? 1.0f : 0.0f;
        #pragma unroll
        for (int k = 0; k < 5; ++k) {
            v2f v = p[k];
            Wx[k] = (v2f){v.x * m, v.y * m};
        }
    }
    const float bias0v = b_ih0[i] + b_hh0[i];
    const float bias1v = b_ih1[i] + b_hh1[i];

    // ---- gathered state (every lane holds full h1(tau-1), h2(tau-2)) ----
    v2f h1p[10], h2p[10];
    #pragma unroll
    for (int k = 0; k < 10; ++k) { h1p[k] = (v2f){0.f, 0.f}; h2p[k] = (v2f){0.f, 0.f}; }

    const float* xr = x + (size_t)samp * (T_ * DIN);

    // 2-slot x pipeline (one timestep row = 5 v2f; rows are 8B-aligned, stride 40B)
    v2f xs[2][5];
    #pragma unroll
    for (int q = 0; q < 5; ++q) {
        xs[0][q] = reinterpret_cast<const v2f*>(xr + 0 * DIN)[q];
        xs[1][q] = reinterpret_cast<const v2f*>(xr + 1 * DIN)[q];
    }

    auto exch_read = [&]() {
        #pragma unroll
        for (int k = 0; k < 5; ++k) {
            v4f v = reinterpret_cast<const v4f*>(hs)[k];          // h1(tau)
            h1p[2*k] = (v2f){v.x, v.y}; h1p[2*k+1] = (v2f){v.z, v.w};
        }
        #pragma unroll
        for (int k = 0; k < 5; ++k) {
            v4f v = reinterpret_cast<const v4f*>(hs + H_)[k];     // h2(tau-1)
            h2p[2*k] = (v2f){v.x, v.y}; h2p[2*k+1] = (v2f){v.z, v.w};
        }
    };

    // one combined step: consume x slot `sl`, prefetch row `tn` into slot `sl`
    auto step = [&](int sl, int tn) {
        v2f xa = (v2f){bias0v, 0.f};
        #pragma unroll
        for (int q = 0; q < 5; ++q) xa = pkfma(xs[sl][q], Wx[q], xa);
        float base = s0 ? (xa.x + xa.y) : bias1v;        // one cndmask

        v2f aE = (v2f){base, 0.f}, aO = (v2f){0.f, 0.f};
        #pragma unroll
        for (int k = 0; k < 5; ++k) {
            aE = pkfma(h1p[2*k],   U[2*k],   aE);
            aO = pkfma(h1p[2*k+1], U[2*k+1], aO);
        }
        #pragma unroll
        for (int k = 0; k < 5; ++k) {
            aE = pkfma(h2p[2*k],   V[2*k],   aE);
            aO = pkfma(h2p[2*k+1], V[2*k+1], aO);
        }
        v2f sm = aE + aO;
        float val = fast_tanh(sm.x + sm.y);

        hs[lane] = val;          // set0 -> hs[0..19]=h1(tau); set1 -> hs[20..39]=h2(tau-1)
        exch_read();             // broadcast read-back (single RT per step)

        #pragma unroll
        for (int q = 0; q < 5; ++q)
            xs[sl][q] = reinterpret_cast<const v2f*>(xr + tn * DIN)[q];
    };

    // ---- peel tau=0: h1(0)=tanh(xp(0)); h2 rows forced to 0 ----
    {
        v2f xa = (v2f){bias0v, 0.f};
        #pragma unroll
        for (int q = 0; q < 5; ++q) xa = pkfma(xs[0][q], Wx[q], xa);
        float val = s0 ? fast_tanh(xa.x + xa.y) : 0.0f;
        hs[lane] = val;
        exch_read();
        #pragma unroll
        for (int q = 0; q < 5; ++q)
            xs[0][q] = reinterpret_cast<const v2f*>(xr + 2 * DIN)[q];  // prefetch tau=2
    }

    // ---- main loop: tau = 1..512 (at tau=512 set1 emits h2(T-1); set0's h1 is dead) ----
    for (int t = 1; t < 513; t += 2) {
        const int tn1 = (t + 2 < T_) ? (t + 2) : (T_ - 1);   // clamp x row
        const int tn2 = (t + 3 < T_) ? (t + 3) : (T_ - 1);
        step(1, tn1);   // tau = t     (odd  -> slot 1)
        step(0, tn2);   // tau = t + 1 (even -> slot 0)
    }

    // ---- FC: every lane holds full h2(T-1) in h2p; lanes 0..1 emit outputs ----
    if (lane < DOUT) {
        const v2f* fw = reinterpret_cast<const v2f*>(fc_w + lane * H_);
        v2f acc = (v2f){fc_b[lane], 0.f};
        #pragma unroll
        for (int k = 0; k < 10; ++k) acc = pkfma(h2p[k], fw[k], acc);
        out[samp * DOUT + lane] = acc.x + acc.y;
    }
}

extern "C" void kernel_launch(void* const* d_in, const int* in_sizes, int n_in,
                              void* d_out, int out_size, void* d_ws, size_t ws_size,
                              hipStream_t stream) {
    (void)in_sizes; (void)n_in; (void)d_ws; (void)ws_size; (void)out_size;
    const float* x     = (const float*)d_in[0];
    const float* w_ih0 = (const float*)d_in[1];
    const float* w_hh0 = (const float*)d_in[2];
    const float* b_ih0 = (const float*)d_in[3];
    const float* b_hh0 = (const float*)d_in[4];
    const float* w_ih1 = (const float*)d_in[5];
    const float* w_hh1 = (const float*)d_in[6];
    const float* b_ih1 = (const float*)d_in[7];
    const float* b_hh1 = (const float*)d_in[8];
    const float* fc_w  = (const float*)d_in[9];
    const float* fc_b  = (const float*)d_in[10];
    float* out = (float*)d_out;

    hipLaunchKernelGGL(rnn_ws, dim3(B_), dim3(64), 0, stream,
                       x, w_ih0, w_hh0, b_ih0, b_hh0,
                       w_ih1, w_hh1, b_ih1, b_hh1, fc_w, fc_b, out);
}

// Round 13
// 136.739 us; speedup vs baseline: 1.5735x; 1.5735x over previous
//
#include <hip/hip_runtime.h>
#include <cstdint>

// Problem constants (from reference)
constexpr int B_   = 4096;
constexpr int T_   = 512;
constexpr int DIN  = 10;
constexpr int H_   = 20;
constexpr int DOUT = 2;

constexpr int SPW = 3;            // samples per wave (3 x 20 = 60 active lanes)
constexpr int CH  = 2;            // timesteps per x-chunk (2*10 floats = 5 float4)
constexpr int XV  = CH * DIN / 4; // float4 prefetch regs per chunk

typedef float    v2f __attribute__((ext_vector_type(2)));
typedef float    v4f __attribute__((ext_vector_type(4)));
typedef _Float16 h2t __attribute__((ext_vector_type(2)));

// One v_pk_fma_f32: two fp32 FMAs per instruction (gfx950 packed-FP32).
__device__ __forceinline__ v2f pkfma(v2f a, v2f b, v2f c) {
    return __builtin_elementwise_fma(a, b, c);
}

// v_dot2_f32_f16: D = a.x*b.x + a.y*b.y + c, f32 accumulate (one instr).
__device__ __forceinline__ float fdot2(h2t a, h2t b, float c) {
#if __has_builtin(__builtin_amdgcn_fdot2)
    return __builtin_amdgcn_fdot2(a, b, c, false);
#else
    return fmaf((float)a.x, (float)b.x, fmaf((float)a.y, (float)b.y, c));
#endif
}

__device__ __forceinline__ float fast_tanh(float v) {
    // tanh(v) = 1 - 2/(exp2(2*log2e*v)+1): exact saturation at +/-inf
    float e = __builtin_amdgcn_exp2f(v * 2.885390082f);
    float r = __builtin_amdgcn_rcpf(e + 1.0f);
    return fmaf(-2.0f, r, 1.0f);
}

union V4H { v4f f; h2t h[4]; };

// Skewed 2-layer RNN, f16 state exchange + v_dot2_f32_f16 dots.
// LDS row per sample: [h1(20) | h2(20)] as f16 = 80 B.
// Per step: 2x ds_write_b16 + 5x ds_read_b128  (DS ops 12 -> 7 per 3 samples)
// DS-pipe throughput per CU is the measured bottleneck (R9/R10/R12 fits).
extern "C" __global__ void __launch_bounds__(64, 1)
rnn_h16(const float* __restrict__ x,
        const float* __restrict__ w_ih0, const float* __restrict__ w_hh0,
        const float* __restrict__ b_ih0, const float* __restrict__ b_hh0,
        const float* __restrict__ w_ih1, const float* __restrict__ w_hh1,
        const float* __restrict__ b_ih1, const float* __restrict__ b_hh1,
        const float* __restrict__ fc_w, const float* __restrict__ fc_b,
        float* __restrict__ out)
{
    const int lane = threadIdx.x;
    const int sl   = lane / H_;          // 0..2 active, 3 = idle lanes 60..63
    const int i    = lane - sl * H_;     // h-index 0..19
    const int samp = blockIdx.x * SPW + sl;
    const int sc   = (samp < B_) ? samp : (B_ - 1);   // clamped for safe loads
    const int slc  = (sl < SPW) ? sl : SPW;           // idle lanes -> spare row

    // row stride 40 halves = 80 B (16B-aligned rows: 80 % 16 == 0)
    __shared__ __align__(16) _Float16 hs[SPW + 1][2 * H_];

    // ---- per-lane weight rows as f16 pairs (one-time convert; ~35 VGPRs) ----
    h2t wh0h[10], wi1h[10], wh1h[10];
    {
        const v4f* p0 = reinterpret_cast<const v4f*>(w_hh0 + i * H_);
        const v4f* p1 = reinterpret_cast<const v4f*>(w_ih1 + i * H_);
        const v4f* p2 = reinterpret_cast<const v4f*>(w_hh1 + i * H_);
        #pragma unroll
        for (int k = 0; k < 5; ++k) {
            v4f a = p0[k];
            wh0h[2*k]   = h2t{(_Float16)a.x, (_Float16)a.y};
            wh0h[2*k+1] = h2t{(_Float16)a.z, (_Float16)a.w};
            v4f b = p1[k];
            wi1h[2*k]   = h2t{(_Float16)b.x, (_Float16)b.y};
            wi1h[2*k+1] = h2t{(_Float16)b.z, (_Float16)b.w};
            v4f c = p2[k];
            wh1h[2*k]   = h2t{(_Float16)c.x, (_Float16)c.y};
            wh1h[2*k+1] = h2t{(_Float16)c.z, (_Float16)c.w};
        }
    }
    // x-projection stays fp32 (x layout fixed; 5 pkfma per step)
    v2f wi0p[DIN / 2];
    {
        const v2f* p = reinterpret_cast<const v2f*>(w_ih0 + i * DIN);
        #pragma unroll
        for (int k = 0; k < DIN / 2; ++k) wi0p[k] = p[k];
    }
    const float bias0 = b_ih0[i] + b_hh0[i];
    const float bias1 = b_ih1[i] + b_hh1[i];

    // ---- gathered state as f16 pairs: h1h = h1(tau-1), h2h = h2(tau-2) ----
    h2t h1h[10], h2h[10];
    #pragma unroll
    for (int k = 0; k < 10; ++k) {
        h1h[k] = h2t{(_Float16)0.f, (_Float16)0.f};
        h2h[k] = h2t{(_Float16)0.f, (_Float16)0.f};
    }

    const v4f* xb = reinterpret_cast<const v4f*>(x + (size_t)sc * (T_ * DIN));

    // ---- prologue: prefetch chunk 0 ----
    v4f xv[XV];
    #pragma unroll
    for (int k = 0; k < XV; ++k) xv[k] = xb[k];

    auto getpair = [&](int p) -> v2f {
        v4f v = xv[p >> 1];
        return (p & 1) ? (v2f){v.z, v.w} : (v2f){v.x, v.y};
    };

    auto consume_xp = [&](float (&xp)[CH]) {
        #pragma unroll
        for (int m = 0; m < CH; ++m) {
            v2f acc = (v2f){bias0, 0.f};
            #pragma unroll
            for (int q = 0; q < DIN / 2; ++q)
                acc = pkfma(getpair(m * (DIN / 2) + q), wi0p[q], acc);
            xp[m] = acc.x + acc.y;
        }
    };

    // read full row (h1(tau) | h2(tau-1)) with 5x ds_read_b128, unpack names
    auto row_read = [&]() {
        V4H r[5];
        #pragma unroll
        for (int k = 0; k < 5; ++k)
            r[k].f = reinterpret_cast<const v4f*>(&hs[slc][0])[k];
        // pairs p = 4k + j ; h1 = pairs 0..9, h2 = pairs 10..19
        #pragma unroll
        for (int k = 0; k < 2; ++k) {
            h1h[4*k+0] = r[k].h[0]; h1h[4*k+1] = r[k].h[1];
            h1h[4*k+2] = r[k].h[2]; h1h[4*k+3] = r[k].h[3];
        }
        h1h[8] = r[2].h[0]; h1h[9] = r[2].h[1];
        h2h[0] = r[2].h[2]; h2h[1] = r[2].h[3];
        #pragma unroll
        for (int k = 0; k < 2; ++k) {
            h2h[2+4*k+0] = r[3+k].h[0]; h2h[2+4*k+1] = r[3+k].h[1];
            h2h[2+4*k+2] = r[3+k].h[2]; h2h[2+4*k+3] = r[3+k].h[3];
        }
    };

    // one skewed step: h1(tau) [L0] and h2(tau-1) [L1], one row exchange
    auto full_step = [&](float xpm) {
        // ---- L0: a = xpm + wh0 . h1(tau-1)  (10 dot2, 2 chains) ----
        float a0 = xpm, a1 = 0.f;
        #pragma unroll
        for (int k = 0; k < 5; ++k) {
            a0 = fdot2(h1h[2*k],   wh0h[2*k],   a0);
            a1 = fdot2(h1h[2*k+1], wh0h[2*k+1], a1);
        }
        float h1n = fast_tanh(a0 + a1);

        // ---- L1 (skewed): b = bias1 + wi1 . h1(tau-1) + wh1 . h2(tau-2) ----
        float b0 = bias1, b1 = 0.f;
        #pragma unroll
        for (int k = 0; k < 5; ++k) {
            b0 = fdot2(h1h[2*k],   wi1h[2*k],   b0);
            b1 = fdot2(h1h[2*k+1], wi1h[2*k+1], b1);
        }
        #pragma unroll
        for (int k = 0; k < 5; ++k) {
            b0 = fdot2(h2h[2*k],   wh1h[2*k],   b0);
            b1 = fdot2(h2h[2*k+1], wh1h[2*k+1], b1);
        }
        float h2n = fast_tanh(b0 + b1);

        // ---- exchange: two b16 writes + 5 b128 row reads ----
        hs[slc][i]      = (_Float16)h1n;
        hs[slc][H_ + i] = (_Float16)h2n;
        row_read();
    };

    // ---- chunk 0, tau=0 peeled: h1(0)=tanh(xp[0]); h2 row zeroed ----
    {
        float xp[CH];
        consume_xp(xp);
        #pragma unroll
        for (int k = 0; k < XV; ++k) xv[k] = xb[(CH * DIN) / 4 + k];  // prefetch chunk 1

        float h1n = fast_tanh(xp[0]);
        hs[slc][i]      = (_Float16)h1n;
        hs[slc][H_ + i] = (_Float16)0.f;
        row_read();

        #pragma unroll
        for (int m = 1; m < CH; ++m) full_step(xp[m]);
    }

    // ---- main loop: chunks t0 = CH .. T-CH ----
    for (int t0 = CH; t0 < T_; t0 += CH) {
        float xp[CH];
        consume_xp(xp);
        {
            const int t0n = (t0 + CH < T_) ? (t0 + CH) : 0;  // clamp, branchless
            #pragma unroll
            for (int k = 0; k < XV; ++k) xv[k] = xb[(t0n * DIN) / 4 + k];
        }
        #pragma unroll
        for (int m = 0; m < CH; ++m) full_step(xp[m]);
    }

    // ---- epilogue: h2(T-1) from h1(T-1) (=h1h) and h2(T-2) (=h2h) ----
    float h2fin[H_];
    {
        float b0 = bias1, b1 = 0.f;
        #pragma unroll
        for (int k = 0; k < 5; ++k) {
            b0 = fdot2(h1h[2*k],   wi1h[2*k],   b0);
            b1 = fdot2(h1h[2*k+1], wi1h[2*k+1], b1);
        }
        #pragma unroll
        for (int k = 0; k < 5; ++k) {
            b0 = fdot2(h2h[2*k],   wh1h[2*k],   b0);
            b1 = fdot2(h2h[2*k+1], wh1h[2*k+1], b1);
        }
        float h2n = fast_tanh(b0 + b1);
        // final exchange in f32 via the same LDS (reuse as raw bytes is messy;
        // simplest: f16 once more -- final output error budget allows it)
        hs[slc][H_ + i] = (_Float16)h2n;
        #pragma unroll
        for (int j = 0; j < H_; ++j) h2fin[j] = (float)hs[slc][H_ + j];
    }

    // ---- FC: lanes i<2 emit out[samp][i] ----
    if (sl < SPW && samp < B_ && i < DOUT) {
        float acc = fc_b[i];
        #pragma unroll
        for (int j = 0; j < H_; ++j) acc = fmaf(h2fin[j], fc_w[i * H_ + j], acc);
        out[samp * DOUT + i] = acc;
    }
}

extern "C" void kernel_launch(void* const* d_in, const int* in_sizes, int n_in,
                              void* d_out, int out_size, void* d_ws, size_t ws_size,
                              hipStream_t stream) {
    (void)in_sizes; (void)n_in; (void)d_ws; (void)ws_size; (void)out_size;
    const float* x     = (const float*)d_in[0];
    const float* w_ih0 = (const float*)d_in[1];
    const float* w_hh0 = (const float*)d_in[2];
    const float* b_ih0 = (const float*)d_in[3];
    const float* b_hh0 = (const float*)d_in[4];
    const float* w_ih1 = (const float*)d_in[5];
    const float* w_hh1 = (const float*)d_in[6];
    const float* b_ih1 = (const float*)d_in[7];
    const float* b_hh1 = (const float*)d_in[8];
    const float* fc_w  = (const float*)d_in[9];
    const float* fc_b  = (const float*)d_in[10];
    float* out = (float*)d_out;

    const int grid = (B_ + SPW - 1) / SPW;   // 1366 single-wave blocks
    hipLaunchKernelGGL(rnn_h16, dim3(grid), dim3(64), 0, stream,
                       x, w_ih0, w_hh0, b_ih0, b_hh0,
                       w_ih1, w_hh1, b_ih1, b_hh1, fc_w, fc_b, out);
}